// Round 10
// baseline (596.944 us; speedup 1.0000x reference)
//
#include <hip/hip_runtime.h>
#include <hip/hip_bf16.h>
#include <hip/hip_fp16.h>

// ScaledDotProductAttention N=M=8192, DK=DV=256, fp32 io.
// R10 = R9 (verified: KV tile 32, counted-vmcnt, 4-wave blocks) + 2 q-sets
// per wave: each wave owns 64 q-rows; every K/V LDS fragment read feeds TWO
// MFMAs (halved LDS bytes per MFMA, doubled per-wave MFMA ILP). ~470 unified
// regs -> 1 wave/SIMD; grid 32 qblks x ng (1 block/CU).

typedef __attribute__((ext_vector_type(16))) float floatx16;
typedef __attribute__((ext_vector_type(8)))  short short8;

union S8u { short8 v; unsigned short u[8]; };

#if __has_builtin(__builtin_amdgcn_exp2f)
#define EXP2F(x) __builtin_amdgcn_exp2f(x)
#else
#define EXP2F(x) exp2f(x)
#endif

__device__ __forceinline__ unsigned short f2bf(float f) {
    unsigned int u = __builtin_bit_cast(unsigned int, f);
    unsigned int r = u + 0x7fffu + ((u >> 16) & 1u);   // RNE
    return (unsigned short)(r >> 16);
}

__device__ __forceinline__ unsigned cvtpk_bf16(float lo, float hi) {
    unsigned r;
    asm("v_cvt_pk_bf16_f32 %0, %1, %2" : "=v"(r) : "v"(lo), "v"(hi));
    return r;
}

__device__ __forceinline__ void gload16(const void* g, void* l) {
    __builtin_amdgcn_global_load_lds(
        (const __attribute__((address_space(1))) unsigned int*)g,
        (__attribute__((address_space(3))) unsigned int*)l, 16, 0, 0);
}

// ---------------- conversion kernels ----------------

__global__ void cvt_bf16_kernel(const float* __restrict__ in,
                                unsigned short* __restrict__ out,
                                float scale, int n8) {
    int i = blockIdx.x * blockDim.x + threadIdx.x;
    if (i >= n8) return;
    const float4* p = reinterpret_cast<const float4*>(in) + (size_t)i * 2;
    float4 a = p[0], b = p[1];
    S8u r;
    r.u[0] = f2bf(a.x * scale); r.u[1] = f2bf(a.y * scale);
    r.u[2] = f2bf(a.z * scale); r.u[3] = f2bf(a.w * scale);
    r.u[4] = f2bf(b.x * scale); r.u[5] = f2bf(b.y * scale);
    r.u[6] = f2bf(b.z * scale); r.u[7] = f2bf(b.w * scale);
    *reinterpret_cast<short8*>(out + (size_t)i * 8) = r.v;
}

// V [8192][256] f32 -> Vt [256][8192] bf16
__global__ void transpose_v_kernel(const float* __restrict__ V,
                                   unsigned short* __restrict__ Vt) {
    __shared__ unsigned short T[64][72];
    const int kv0 = blockIdx.x * 64;
    const int v0  = blockIdx.y * 64;
    const int tid = threadIdx.x;           // 256
#pragma unroll
    for (int it = 0; it < 4; ++it) {
        int flat = it * 256 + tid;
        int r  = flat >> 4;
        int c4 = (flat & 15) * 4;
        float4 f = *reinterpret_cast<const float4*>(
            V + (size_t)(kv0 + r) * 256 + v0 + c4);
        T[c4 + 0][r] = f2bf(f.x);
        T[c4 + 1][r] = f2bf(f.y);
        T[c4 + 2][r] = f2bf(f.z);
        T[c4 + 3][r] = f2bf(f.w);
    }
    __syncthreads();
#pragma unroll
    for (int it = 0; it < 2; ++it) {
        int flat = it * 256 + tid;
        int r  = flat >> 3;
        int c8 = (flat & 7) * 8;
        short8 v8 = *reinterpret_cast<const short8*>(&T[r][c8]);
        *reinterpret_cast<short8*>(Vt + (size_t)(v0 + r) * 8192 + kv0 + c8) = v8;
    }
}

// ---------------- main attention kernel ----------------

#define MFMA_B16 __builtin_amdgcn_mfma_f32_32x32x16_bf16

__global__ __launch_bounds__(256, 1)
void attn_kernel(const float* __restrict__ Qf,            // [8192][256] fp32
                 const unsigned short* __restrict__ Kb,   // [8192][256] bf16
                 const unsigned short* __restrict__ VtG,  // [256][8192] bf16
                 __half* __restrict__ Opart,              // [NG][8192][256]
                 float* __restrict__ Ml,                  // [NG][8192][2]
                 int kv_span, int gshift) {
    // [buf][ K 16KB ] and [buf][ Vt 16KB ]  (tile = 32 kv)
    __shared__ __align__(16) unsigned char kbuf[2][16384];
    __shared__ __align__(16) unsigned char vbuf[2][16384];

    const int tid  = threadIdx.x;
    const int lane = tid & 63;
    const int w    = tid >> 6;     // 0..3
    const int l31  = lane & 31;
    const int h    = lane >> 5;    // 0/1

    const int ngm1 = (1 << gshift) - 1;
    const int id   = blockIdx.x + 32 * blockIdx.y;
    const int g    = id & ngm1;          // XCD-affine
    const int qblk = id >> gshift;       // 0..31
    const int kv_begin = g * kv_span;
    const int tiles = kv_span >> 5;
    const int q0 = qblk * 256 + w * 64;  // wave owns q0..q0+63

    // Q as B-fragments for BOTH q-sets (scale = log2(e)/16, exp2 domain)
    const float qs = 0.09016844005556021f;
    short8 qf0[16], qf1[16];
    {
        const float* qp0 = Qf + (size_t)(q0 + l31) * 256 + h * 8;
        const float* qp1 = Qf + (size_t)(q0 + 32 + l31) * 256 + h * 8;
#pragma unroll
        for (int ds = 0; ds < 16; ++ds) {
            float4 f0 = *reinterpret_cast<const float4*>(qp0 + ds * 16);
            float4 f1 = *reinterpret_cast<const float4*>(qp0 + ds * 16 + 4);
            uint4 uu;
            uu.x = cvtpk_bf16(f0.x * qs, f0.y * qs);
            uu.y = cvtpk_bf16(f0.z * qs, f0.w * qs);
            uu.z = cvtpk_bf16(f1.x * qs, f1.y * qs);
            uu.w = cvtpk_bf16(f1.z * qs, f1.w * qs);
            qf0[ds] = __builtin_bit_cast(short8, uu);
            float4 g0 = *reinterpret_cast<const float4*>(qp1 + ds * 16);
            float4 g1 = *reinterpret_cast<const float4*>(qp1 + ds * 16 + 4);
            uu.x = cvtpk_bf16(g0.x * qs, g0.y * qs);
            uu.y = cvtpk_bf16(g0.z * qs, g0.w * qs);
            uu.z = cvtpk_bf16(g1.x * qs, g1.y * qs);
            uu.w = cvtpk_bf16(g1.z * qs, g1.w * qs);
            qf1[ds] = __builtin_bit_cast(short8, uu);
        }
    }

    floatx16 o0[8], o1[8];
#pragma unroll
    for (int vt = 0; vt < 8; ++vt)
#pragma unroll
        for (int r = 0; r < 16; ++r) { o0[vt][r] = 0.f; o1[vt][r] = 0.f; }
    float m0r = -1e30f, l0r = 0.f, m1r = -1e30f, l1r = 0.f;

    // staging offsets: 16B-chunk j = i*256 + tid  (identical to R9, verified)
    int offk[4], offv[4];
#pragma unroll
    for (int i = 0; i < 4; ++i) {
        int j  = i * 256 + tid;
        int rk = j >> 5, ck = (j & 31) ^ (rk & 7);
        offk[i] = rk * 256 + ck * 8;
        int rv = j >> 2, cv = (j & 3) ^ ((rv >> 1) & 3);
        offv[i] = rv * 8192 + cv * 8;
    }

    auto STAGEK = [&](int kv0, int bufsel) {
        const unsigned short* ks = Kb + (size_t)kv0 * 256;
#pragma unroll
        for (int i = 0; i < 4; ++i)
            gload16(ks + offk[i], &kbuf[bufsel][(i * 256 + w * 64) * 16]);
    };
    auto STAGEV = [&](int kv0, int bufsel) {
        const unsigned short* vs = VtG + kv0;
#pragma unroll
        for (int i = 0; i < 4; ++i)
            gload16(vs + offv[i], &vbuf[bufsel][(i * 256 + w * 64) * 16]);
    };

    // ---- prologue: K(0) needed now, V(0) may stay in flight ----
    STAGEK(kv_begin, 0);
    STAGEV(kv_begin, 0);
    asm volatile("s_waitcnt vmcnt(4)" ::: "memory");
    __builtin_amdgcn_s_barrier();

    const int swz  = l31 & 7;          // K-read swizzle
    const int vswz = (l31 >> 1) & 3;   // V-read swizzle

    auto buildPA = [&](const floatx16& sv, int rbase) -> short8 {
        unsigned cpk0 = cvtpk_bf16(sv[rbase + 0], sv[rbase + 1]);
        unsigned cpk1 = cvtpk_bf16(sv[rbase + 2], sv[rbase + 3]);
        unsigned cpk2 = cvtpk_bf16(sv[rbase + 4], sv[rbase + 5]);
        unsigned cpk3 = cvtpk_bf16(sv[rbase + 6], sv[rbase + 7]);
        uint4 uu;
#if __has_builtin(__builtin_amdgcn_permlane32_swap)
        auto r02 = __builtin_amdgcn_permlane32_swap((int)cpk0, (int)cpk2, false, false);
        auto r13 = __builtin_amdgcn_permlane32_swap((int)cpk1, (int)cpk3, false, false);
        uu.x = (unsigned)r02[0]; uu.y = (unsigned)r13[0];
        uu.z = (unsigned)r02[1]; uu.w = (unsigned)r13[1];
#else
        unsigned send0 = h ? cpk0 : cpk2;
        unsigned send1 = h ? cpk1 : cpk3;
        unsigned r0 = (unsigned)__shfl_xor((int)send0, 32);
        unsigned r1 = (unsigned)__shfl_xor((int)send1, 32);
        uu.x = h ? r0 : cpk0;
        uu.y = h ? r1 : cpk1;
        uu.z = h ? cpk2 : r0;
        uu.w = h ? cpk3 : r1;
#endif
        return __builtin_bit_cast(short8, uu);
    };

    // online-softmax (exp2 domain) for one q-set; verified R9 code
    auto SM = [&](floatx16& sv, float& m_run, float& l_run, floatx16* o) {
        float t4[4];
#pragma unroll
        for (int i = 0; i < 4; ++i)
            t4[i] = fmaxf(fmaxf(sv[i], sv[i + 4]),
                          fmaxf(sv[i + 8], sv[i + 12]));
        float mt = fmaxf(fmaxf(t4[0], t4[1]), fmaxf(t4[2], t4[3]));
        mt = fmaxf(mt, __shfl_xor(mt, 32));
        if (__any(mt > m_run + 11.5f)) {      // defer-max (log2 units)
            float mnew = fmaxf(m_run, mt);
            float al = EXP2F(m_run - mnew);
            m_run = mnew;
            l_run *= al;
#pragma unroll
            for (int reg = 0; reg < 16; ++reg) {
                int srcl = ((reg & 3) + 8 * (reg >> 2)) + 4 * h;
                float alr = __shfl(al, srcl);
#pragma unroll
                for (int vt = 0; vt < 8; ++vt) o[vt][reg] *= alr;
            }
        }
#pragma unroll
        for (int r = 0; r < 16; ++r) sv[r] = EXP2F(sv[r] - m_run);
        float u[4];
#pragma unroll
        for (int i = 0; i < 4; ++i)
            u[i] = (sv[i] + sv[i + 4]) + (sv[i + 8] + sv[i + 12]);
        float lt = (u[0] + u[1]) + (u[2] + u[3]);
        lt += __shfl_xor(lt, 32);
        l_run += lt;
    };

    for (int t = 0; t < tiles; ++t) {
        const int cur = t & 1;
        const int nxt = cur ^ 1;
        const int tn  = (t + 1 < tiles) ? t + 1 : t;  // clamp: dummy restage

        // ---- phase 1: issue K(t+1); QK^T (both q-sets) + softmax ----
        STAGEK(kv_begin + tn * 32, nxt);

        const unsigned char* kl = kbuf[cur];
        floatx16 s0, s1;
#pragma unroll
        for (int r = 0; r < 16; ++r) { s0[r] = 0.f; s1[r] = 0.f; }
        __builtin_amdgcn_s_setprio(1);
#pragma unroll
        for (int ds = 0; ds < 16; ++ds) {
            int c0 = (ds * 2 + h) ^ swz;
            short8 a0 = *reinterpret_cast<const short8*>(
                kl + (size_t)l31 * 512 + c0 * 16);
            s0 = MFMA_B16(a0, qf0[ds], s0, 0, 0, 0);
            s1 = MFMA_B16(a0, qf1[ds], s1, 0, 0, 0);
        }
        __builtin_amdgcn_s_setprio(0);

        SM(s0, m0r, l0r, o0);
        SM(s1, m1r, l1r, o1);

        // V(t) must be visible before PV; K(t+1) stays in flight
        asm volatile("s_waitcnt vmcnt(4)" ::: "memory");
        __builtin_amdgcn_s_barrier();

        // ---- phase 2: issue V(t+1); PV (both q-sets share each V read) ----
        STAGEV(kv_begin + tn * 32, nxt);

        const unsigned char* vl = vbuf[cur];
        __builtin_amdgcn_s_setprio(1);
#pragma unroll
        for (int kk = 0; kk < 2; ++kk) {
            short8 pa0 = buildPA(s0, kk * 8);
            short8 pa1 = buildPA(s1, kk * 8);
            int cvs = (kk * 2 + h) ^ vswz;
#pragma unroll
            for (int vt = 0; vt < 8; ++vt) {
                short8 b = *reinterpret_cast<const short8*>(
                    vl + (size_t)(vt * 32 + l31) * 64 + cvs * 16);
                o0[vt] = MFMA_B16(pa0, b, o0[vt], 0, 0, 0);
                o1[vt] = MFMA_B16(pa1, b, o1[vt], 0, 0, 0);
            }
        }
        __builtin_amdgcn_s_setprio(0);

        // K(t+1) must be visible before next QK^T; V(t+1) stays in flight
        asm volatile("s_waitcnt vmcnt(4)" ::: "memory");
        __builtin_amdgcn_s_barrier();
    }

    // ---- epilogue: normalized fp16 partials + (m,l) per q-set ----
    const size_t gq = (size_t)g * 8192;
    {
        float linv = 1.0f / l0r;
#pragma unroll
        for (int reg = 0; reg < 16; ++reg) {
            int row = (reg & 3) + 8 * (reg >> 2) + 4 * h;
            float li = __shfl(linv, row);
#pragma unroll
            for (int vt = 0; vt < 8; ++vt)
                Opart[(gq + q0 + row) * 256 + vt * 32 + l31] =
                    __float2half_rn(o0[vt][reg] * li);
        }
    }
    {
        float linv = 1.0f / l1r;
#pragma unroll
        for (int reg = 0; reg < 16; ++reg) {
            int row = (reg & 3) + 8 * (reg >> 2) + 4 * h;
            float li = __shfl(linv, row);
#pragma unroll
            for (int vt = 0; vt < 8; ++vt)
                Opart[(gq + q0 + 32 + row) * 256 + vt * 32 + l31] =
                    __float2half_rn(o1[vt][reg] * li);
        }
    }
    if (h == 0) {
        size_t idx0 = (gq + q0 + l31) * 2;
        Ml[idx0]     = m0r;   // log2 domain
        Ml[idx0 + 1] = l0r;
        size_t idx1 = (gq + q0 + 32 + l31) * 2;
        Ml[idx1]     = m1r;
        Ml[idx1 + 1] = l1r;
    }
}

// ---------------- merge kernel ----------------

__global__ void merge_kernel(const __half* __restrict__ Opart,
                             const float* __restrict__ Ml,
                             float* __restrict__ out, int ngroups) {
    int row = blockIdx.x;
    int col = threadIdx.x;
    float m = -1e30f;
    for (int g = 0; g < ngroups; ++g)
        m = fmaxf(m, Ml[((size_t)g * 8192 + row) * 2]);
    float den = 0.f, acc = 0.f;
    for (int g = 0; g < ngroups; ++g) {
        float wg = EXP2F(Ml[((size_t)g * 8192 + row) * 2] - m) *
                   Ml[((size_t)g * 8192 + row) * 2 + 1];
        den += wg;
        acc += wg * __half2float(Opart[((size_t)g * 8192 + row) * 256 + col]);
    }
    out[(size_t)row * 256 + col] = acc / den;
}

// ---------------- launcher ----------------

extern "C" void kernel_launch(void* const* d_in, const int* in_sizes, int n_in,
                              void* d_out, int out_size, void* d_ws, size_t ws_size,
                              hipStream_t stream) {
    const float* Q = (const float*)d_in[0];
    const float* K = (const float*)d_in[1];
    const float* V = (const float*)d_in[2];
    float* out = (float*)d_out;

    unsigned short* Kb = (unsigned short*)d_ws;            // 4 MiB
    unsigned short* Vt = Kb + (size_t)8192 * 256;          // 4 MiB

    const size_t base = (size_t)8192 * 256 * 2 * 2;        // 8 MiB
    const size_t osz  = (size_t)8192 * 256 * 2;            // 4 MiB/group (fp16)
    const size_t mlsz = (size_t)8192 * 2 * 4;              // 64 KiB/group

    int gshift = 3;
    for (; gshift > 0; --gshift)
        if (base + ((osz + mlsz) << gshift) <= ws_size) break;
    int ng = 1 << gshift;

    __half* Opart = (__half*)((char*)d_ws + base);
    float*  Mlp   = (float*)((char*)d_ws + base + osz * (size_t)ng);

    const int n8 = 8192 * 256 / 8;
    cvt_bf16_kernel<<<n8 / 256, 256, 0, stream>>>(K, Kb, 1.0f, n8);
    transpose_v_kernel<<<dim3(128, 4), 256, 0, stream>>>(V, Vt);
    attn_kernel<<<dim3(32, ng), 256, 0, stream>>>(Q, Kb, Vt, Opart, Mlp,
                                                  8192 / ng, gshift);
    merge_kernel<<<8192, 256, 0, stream>>>(Opart, Mlp, out, ng);
}

// Round 11
// 159.338 us; speedup vs baseline: 3.7464x; 3.7464x over previous
//
#include <hip/hip_runtime.h>
#include <hip/hip_bf16.h>
#include <hip/hip_fp16.h>

// ScaledDotProductAttention N=M=8192, DK=DV=256, fp32 io.
// R11: 16x16x32-MFMA restructure for 3 waves/SIMD. Wave = 16 q x 256 v
// (~160 regs: o 64 + qf 32 + s 8). Block = 4 waves = 64 q; LDS 48KB
// (K dbuf 32K + V single 16K) -> 3 blocks/CU = 3 independent barrier
// domains per SIMD. Swapped QK^T (S^T = K x Q^T, q = C-col = l15),
// in-register P exchange (8 shfl) -> PV A-frags. Counted-vmcnt schedule.

typedef __attribute__((ext_vector_type(4)))  float floatx4;
typedef __attribute__((ext_vector_type(8)))  short short8;

union S8u { short8 v; unsigned short u[8]; };

#if __has_builtin(__builtin_amdgcn_exp2f)
#define EXP2F(x) __builtin_amdgcn_exp2f(x)
#else
#define EXP2F(x) exp2f(x)
#endif

__device__ __forceinline__ unsigned short f2bf(float f) {
    unsigned int u = __builtin_bit_cast(unsigned int, f);
    unsigned int r = u + 0x7fffu + ((u >> 16) & 1u);   // RNE
    return (unsigned short)(r >> 16);
}

__device__ __forceinline__ unsigned cvtpk_bf16(float lo, float hi) {
    unsigned r;
    asm("v_cvt_pk_bf16_f32 %0, %1, %2" : "=v"(r) : "v"(lo), "v"(hi));
    return r;
}

__device__ __forceinline__ void gload16(const void* g, void* l) {
    __builtin_amdgcn_global_load_lds(
        (const __attribute__((address_space(1))) unsigned int*)g,
        (__attribute__((address_space(3))) unsigned int*)l, 16, 0, 0);
}

// ---------------- conversion kernels ----------------

__global__ void cvt_bf16_kernel(const float* __restrict__ in,
                                unsigned short* __restrict__ out,
                                float scale, int n8) {
    int i = blockIdx.x * blockDim.x + threadIdx.x;
    if (i >= n8) return;
    const float4* p = reinterpret_cast<const float4*>(in) + (size_t)i * 2;
    float4 a = p[0], b = p[1];
    S8u r;
    r.u[0] = f2bf(a.x * scale); r.u[1] = f2bf(a.y * scale);
    r.u[2] = f2bf(a.z * scale); r.u[3] = f2bf(a.w * scale);
    r.u[4] = f2bf(b.x * scale); r.u[5] = f2bf(b.y * scale);
    r.u[6] = f2bf(b.z * scale); r.u[7] = f2bf(b.w * scale);
    *reinterpret_cast<short8*>(out + (size_t)i * 8) = r.v;
}

// V [8192][256] f32 -> Vt [256][8192] bf16
__global__ void transpose_v_kernel(const float* __restrict__ V,
                                   unsigned short* __restrict__ Vt) {
    __shared__ unsigned short T[64][72];
    const int kv0 = blockIdx.x * 64;
    const int v0  = blockIdx.y * 64;
    const int tid = threadIdx.x;           // 256
#pragma unroll
    for (int it = 0; it < 4; ++it) {
        int flat = it * 256 + tid;
        int r  = flat >> 4;
        int c4 = (flat & 15) * 4;
        float4 f = *reinterpret_cast<const float4*>(
            V + (size_t)(kv0 + r) * 256 + v0 + c4);
        T[c4 + 0][r] = f2bf(f.x);
        T[c4 + 1][r] = f2bf(f.y);
        T[c4 + 2][r] = f2bf(f.z);
        T[c4 + 3][r] = f2bf(f.w);
    }
    __syncthreads();
#pragma unroll
    for (int it = 0; it < 2; ++it) {
        int flat = it * 256 + tid;
        int r  = flat >> 3;
        int c8 = (flat & 7) * 8;
        short8 v8 = *reinterpret_cast<const short8*>(&T[r][c8]);
        *reinterpret_cast<short8*>(Vt + (size_t)(v0 + r) * 8192 + kv0 + c8) = v8;
    }
}

// ---------------- main attention kernel ----------------

#define MFMA16 __builtin_amdgcn_mfma_f32_16x16x32_bf16

__global__ __launch_bounds__(256, 3)
void attn_kernel(const float* __restrict__ Qf,            // [8192][256] fp32
                 const unsigned short* __restrict__ Kb,   // [8192][256] bf16
                 const unsigned short* __restrict__ VtG,  // [256][8192] bf16
                 __half* __restrict__ Opart,              // [NG][8192][256]
                 float* __restrict__ Ml,                  // [NG][8192][2]
                 int kv_span, int gshift) {
    __shared__ __align__(16) unsigned char kbuf[2][16384];  // K tile 32x512B dbuf
    __shared__ __align__(16) unsigned char vbuf[16384];     // Vt tile 256x64B

    const int tid  = threadIdx.x;
    const int lane = tid & 63;
    const int w    = tid >> 6;     // 0..3
    const int l15  = lane & 15;
    const int lg   = lane >> 4;    // 0..3

    const int ngm1 = (1 << gshift) - 1;
    const int id   = blockIdx.x + 128 * blockIdx.y;
    const int g    = id & ngm1;          // XCD-affine
    const int qblk = id >> gshift;       // 0..127
    const int kv_begin = g * kv_span;
    const int tiles = kv_span >> 5;
    const int q0 = qblk * 64 + w * 16;   // wave owns 16 q-rows

    // Q as B-frags: col=q=l15, k=d = ds*32 + lg*8 + e  (scale log2(e)/16)
    const float qs = 0.09016844005556021f;
    short8 qf[8];
    {
        const float* qp = Qf + (size_t)(q0 + l15) * 256 + lg * 8;
#pragma unroll
        for (int ds = 0; ds < 8; ++ds) {
            float4 f0 = *reinterpret_cast<const float4*>(qp + ds * 32);
            float4 f1 = *reinterpret_cast<const float4*>(qp + ds * 32 + 4);
            uint4 uu;
            uu.x = cvtpk_bf16(f0.x * qs, f0.y * qs);
            uu.y = cvtpk_bf16(f0.z * qs, f0.w * qs);
            uu.z = cvtpk_bf16(f1.x * qs, f1.y * qs);
            uu.w = cvtpk_bf16(f1.z * qs, f1.w * qs);
            qf[ds] = __builtin_bit_cast(short8, uu);
        }
    }

    floatx4 o[16];
#pragma unroll
    for (int vt = 0; vt < 16; ++vt) o[vt] = floatx4{0.f, 0.f, 0.f, 0.f};
    float m_run = -1e30f, l_run = 0.f;

    // staging offsets (verified R9 maps): 16B-chunk j = i*256 + tid
    //   K tile [32][512B]: rk=j>>5, src chunk (j&31)^(rk&7)
    //   V tile [256][64B]: rv=j>>2, src chunk (j&3)^((rv>>1)&3)
    int offk[4], offv[4];
#pragma unroll
    for (int i = 0; i < 4; ++i) {
        int j  = i * 256 + tid;
        int rk = j >> 5, ck = (j & 31) ^ (rk & 7);
        offk[i] = rk * 256 + ck * 8;
        int rv = j >> 2, cv = (j & 3) ^ ((rv >> 1) & 3);
        offv[i] = rv * 8192 + cv * 8;
    }

    auto STAGEK = [&](int kv0, int bufsel) {
        const unsigned short* ks = Kb + (size_t)kv0 * 256;
#pragma unroll
        for (int i = 0; i < 4; ++i)
            gload16(ks + offk[i], &kbuf[bufsel][(i * 256 + w * 64) * 16]);
    };
    auto STAGEV = [&](int kv0) {
        const unsigned short* vs = VtG + kv0;
#pragma unroll
        for (int i = 0; i < 4; ++i)
            gload16(vs + offv[i], &vbuf[(i * 256 + w * 64) * 16]);
    };

    // ---- prologue ----
    STAGEK(kv_begin, 0);
    asm volatile("s_waitcnt vmcnt(0)" ::: "memory");
    __builtin_amdgcn_s_barrier();

    const int swzK = l15 & 7;          // rows l15 and l15+16 share &7
    const int vswz = (l15 >> 1) & 3;
    const int src1 = l15 + (((lg << 1) & 3) << 4);
    const int src2 = l15 + ((((lg << 1) + 1) & 3) << 4);

    for (int t = 0; t < tiles; ++t) {
        const int cur = t & 1;
        const int nxt = cur ^ 1;
        const int tn  = (t + 1 < tiles) ? t + 1 : t;   // dummy restage on last

        // issue V(t) then K(t+1): oldest 4 = V(t)
        STAGEV(kv_begin + t * 32);
        STAGEK(kv_begin + tn * 32, nxt);

        // ---- QK^T: S^T[32kv x 16q], two C-tiles (kv 0..15 / 16..31) ----
        const unsigned char* kl = kbuf[cur];
        floatx4 sA = floatx4{0.f, 0.f, 0.f, 0.f};
        floatx4 sB = floatx4{0.f, 0.f, 0.f, 0.f};
        __builtin_amdgcn_s_setprio(1);
#pragma unroll
        for (int ds = 0; ds < 8; ++ds) {
            int c0 = (ds * 4 + lg) ^ swzK;
            short8 aA = *reinterpret_cast<const short8*>(
                kl + (size_t)l15 * 512 + c0 * 16);
            short8 aB = *reinterpret_cast<const short8*>(
                kl + (size_t)(l15 + 16) * 512 + c0 * 16);
            sA = MFMA16(aA, qf[ds], sA, 0, 0, 0);
            sB = MFMA16(aB, qf[ds], sB, 0, 0, 0);
        }
        __builtin_amdgcn_s_setprio(0);

        // ---- online softmax (exp2 domain); q = l15, copies across lg ----
        {
            float m0 = fmaxf(fmaxf(sA[0], sA[1]), fmaxf(sA[2], sA[3]));
            float m1 = fmaxf(fmaxf(sB[0], sB[1]), fmaxf(sB[2], sB[3]));
            float mt = fmaxf(m0, m1);
            mt = fmaxf(mt, __shfl_xor(mt, 16));
            mt = fmaxf(mt, __shfl_xor(mt, 32));
            if (__any(mt > m_run + 11.5f)) {       // defer-max (log2 units)
                float mnew = fmaxf(m_run, mt);
                float al = EXP2F(m_run - mnew);
                m_run = mnew;
                l_run *= al;
#pragma unroll
                for (int r = 0; r < 4; ++r) {
                    float alr = __shfl(al, lg * 4 + r);   // al for q = lg*4+r
#pragma unroll
                    for (int vt = 0; vt < 16; ++vt) o[vt][r] *= alr;
                }
            }
#pragma unroll
            for (int r = 0; r < 4; ++r) sA[r] = EXP2F(sA[r] - m_run);
#pragma unroll
            for (int r = 0; r < 4; ++r) sB[r] = EXP2F(sB[r] - m_run);
            float lt = ((sA[0] + sA[1]) + (sA[2] + sA[3])) +
                       ((sB[0] + sB[1]) + (sB[2] + sB[3]));
            lt += __shfl_xor(lt, 16);
            lt += __shfl_xor(lt, 32);
            l_run += lt;
        }

        // ---- build PV A-frag: lane needs P[q=l15][kv=8lg..8lg+7] ----
        // lane (l15,lg') holds tileA kv{4lg',4lg'+1}(a0) {4lg'+2,+3}(a1),
        // tileB kv{16+4lg',..}(b0,b1). dest kv 8lg+..: tileA for lg<2, else B.
        short8 pa;
        {
            unsigned a0 = cvtpk_bf16(sA[0], sA[1]);
            unsigned a1 = cvtpk_bf16(sA[2], sA[3]);
            unsigned b0 = cvtpk_bf16(sB[0], sB[1]);
            unsigned b1 = cvtpk_bf16(sB[2], sB[3]);
            unsigned x0 = (unsigned)__shfl((int)a0, src1);
            unsigned y0 = (unsigned)__shfl((int)b0, src1);
            unsigned x1 = (unsigned)__shfl((int)a1, src1);
            unsigned y1 = (unsigned)__shfl((int)b1, src1);
            unsigned x2 = (unsigned)__shfl((int)a0, src2);
            unsigned y2 = (unsigned)__shfl((int)b0, src2);
            unsigned x3 = (unsigned)__shfl((int)a1, src2);
            unsigned y3 = (unsigned)__shfl((int)b1, src2);
            uint4 uu;
            uu.x = (lg < 2) ? x0 : y0;
            uu.y = (lg < 2) ? x1 : y1;
            uu.z = (lg < 2) ? x2 : y2;
            uu.w = (lg < 2) ? x3 : y3;
            pa = __builtin_bit_cast(short8, uu);
        }

        // V(t) landed (oldest 4); K(t+1) may stay in flight
        asm volatile("s_waitcnt vmcnt(4)" ::: "memory");
        __builtin_amdgcn_s_barrier();

        // ---- PV: O[16q x 256v] += P[16x32] * V[32x256]; 16 indep MFMAs ----
        __builtin_amdgcn_s_setprio(1);
#pragma unroll
        for (int vt = 0; vt < 16; ++vt) {
            int cv = lg ^ vswz;
            short8 b = *reinterpret_cast<const short8*>(
                &vbuf[(size_t)(vt * 16 + l15) * 64 + cv * 16]);
            o[vt] = MFMA16(pa, b, o[vt], 0, 0, 0);
        }
        __builtin_amdgcn_s_setprio(0);

        // K(t+1) landed before next QK^T; vbuf free for next STAGEV
        asm volatile("s_waitcnt vmcnt(0)" ::: "memory");
        __builtin_amdgcn_s_barrier();
    }

    // ---- epilogue: normalized fp16 partial + (m,l) fp32 ----
    const size_t gq = (size_t)g * 8192;
    float linv = 1.0f / l_run;
#pragma unroll
    for (int r = 0; r < 4; ++r) {
        int row = lg * 4 + r;                     // q = row (C/D row mapping)
        float li = __shfl(linv, row);
#pragma unroll
        for (int vt = 0; vt < 16; ++vt)
            Opart[(gq + q0 + row) * 256 + vt * 16 + l15] =
                __float2half_rn(o[vt][r] * li);
    }
    if (lg == 0) {
        size_t idx = (gq + q0 + l15) * 2;
        Ml[idx]     = m_run;   // log2 domain
        Ml[idx + 1] = l_run;
    }
}

// ---------------- merge kernel ----------------

__global__ void merge_kernel(const __half* __restrict__ Opart,
                             const float* __restrict__ Ml,
                             float* __restrict__ out, int ngroups) {
    int row = blockIdx.x;
    int col = threadIdx.x;
    float m = -1e30f;
    for (int g = 0; g < ngroups; ++g)
        m = fmaxf(m, Ml[((size_t)g * 8192 + row) * 2]);
    float den = 0.f, acc = 0.f;
    for (int g = 0; g < ngroups; ++g) {
        float wg = EXP2F(Ml[((size_t)g * 8192 + row) * 2] - m) *
                   Ml[((size_t)g * 8192 + row) * 2 + 1];
        den += wg;
        acc += wg * __half2float(Opart[((size_t)g * 8192 + row) * 256 + col]);
    }
    out[(size_t)row * 256 + col] = acc / den;
}

// ---------------- launcher ----------------

extern "C" void kernel_launch(void* const* d_in, const int* in_sizes, int n_in,
                              void* d_out, int out_size, void* d_ws, size_t ws_size,
                              hipStream_t stream) {
    const float* Q = (const float*)d_in[0];
    const float* K = (const float*)d_in[1];
    const float* V = (const float*)d_in[2];
    float* out = (float*)d_out;

    unsigned short* Kb = (unsigned short*)d_ws;            // 4 MiB
    unsigned short* Vt = Kb + (size_t)8192 * 256;          // 4 MiB

    const size_t base = (size_t)8192 * 256 * 2 * 2;        // 8 MiB
    const size_t osz  = (size_t)8192 * 256 * 2;            // 4 MiB/group (fp16)
    const size_t mlsz = (size_t)8192 * 2 * 4;              // 64 KiB/group

    int gshift = 3;
    for (; gshift > 0; --gshift)
        if (base + ((osz + mlsz) << gshift) <= ws_size) break;
    int ng = 1 << gshift;

    __half* Opart = (__half*)((char*)d_ws + base);
    float*  Mlp   = (float*)((char*)d_ws + base + osz * (size_t)ng);

    const int n8 = 8192 * 256 / 8;
    cvt_bf16_kernel<<<n8 / 256, 256, 0, stream>>>(K, Kb, 1.0f, n8);
    transpose_v_kernel<<<dim3(128, 4), 256, 0, stream>>>(V, Vt);
    attn_kernel<<<dim3(128, ng), 256, 0, stream>>>(Q, Kb, Vt, Opart, Mlp,
                                                   8192 / ng, gshift);
    merge_kernel<<<8192, 256, 0, stream>>>(Opart, Mlp, out, ng);
}

// Round 14
// 123.871 us; speedup vs baseline: 4.8191x; 1.2863x over previous
//
#include <hip/hip_runtime.h>
#include <hip/hip_bf16.h>
#include <hip/hip_fp16.h>

// ScaledDotProductAttention N=M=8192, DK=DV=256, fp32 io.
// R14 = attn_kernel verbatim from verified R9 (113us attn; 2 blocks/CU,
// KV tile 32, counted-vmcnt schedule) + fused prep kernel (K-cvt folded
// into V-transpose; one launch saved) + __half2-vectorized merge.

typedef __attribute__((ext_vector_type(16))) float floatx16;
typedef __attribute__((ext_vector_type(8)))  short short8;

union S8u { short8 v; unsigned short u[8]; };

#if __has_builtin(__builtin_amdgcn_exp2f)
#define EXP2F(x) __builtin_amdgcn_exp2f(x)
#else
#define EXP2F(x) exp2f(x)
#endif

__device__ __forceinline__ unsigned short f2bf(float f) {
    unsigned int u = __builtin_bit_cast(unsigned int, f);
    unsigned int r = u + 0x7fffu + ((u >> 16) & 1u);   // RNE
    return (unsigned short)(r >> 16);
}

__device__ __forceinline__ unsigned cvtpk_bf16(float lo, float hi) {
    unsigned r;
    asm("v_cvt_pk_bf16_f32 %0, %1, %2" : "=v"(r) : "v"(lo), "v"(hi));
    return r;
}

__device__ __forceinline__ void gload16(const void* g, void* l) {
    __builtin_amdgcn_global_load_lds(
        (const __attribute__((address_space(1))) unsigned int*)g,
        (__attribute__((address_space(3))) unsigned int*)l, 16, 0, 0);
}

// ---------------- fused prep kernel: V transpose + K cvt ----------------

__global__ void prep_kernel(const float* __restrict__ K,
                            const float* __restrict__ V,
                            unsigned short* __restrict__ Kb,
                            unsigned short* __restrict__ Vt) {
    __shared__ unsigned short T[64][72];
    const int kv0 = blockIdx.x * 64;
    const int v0  = blockIdx.y * 64;
    const int tid = threadIdx.x;           // 256
    // ---- V transpose (verified R1 code) ----
#pragma unroll
    for (int it = 0; it < 4; ++it) {
        int flat = it * 256 + tid;
        int r  = flat >> 4;
        int c4 = (flat & 15) * 4;
        float4 f = *reinterpret_cast<const float4*>(
            V + (size_t)(kv0 + r) * 256 + v0 + c4);
        T[c4 + 0][r] = f2bf(f.x);
        T[c4 + 1][r] = f2bf(f.y);
        T[c4 + 2][r] = f2bf(f.z);
        T[c4 + 3][r] = f2bf(f.w);
    }
    __syncthreads();
#pragma unroll
    for (int it = 0; it < 2; ++it) {
        int flat = it * 256 + tid;
        int r  = flat >> 3;
        int c8 = (flat & 7) * 8;
        short8 v8 = *reinterpret_cast<const short8*>(&T[r][c8]);
        *reinterpret_cast<short8*>(Vt + (size_t)(v0 + r) * 8192 + kv0 + c8) = v8;
    }
    // ---- K conversion slice: 512 chunks-of-8 per block ----
    const int bid = blockIdx.x + 128 * blockIdx.y;   // 0..511
#pragma unroll
    for (int it = 0; it < 2; ++it) {
        int i = bid * 512 + it * 256 + tid;          // 0..262143
        const float4* p = reinterpret_cast<const float4*>(K) + (size_t)i * 2;
        float4 a = p[0], b = p[1];
        S8u r;
        r.u[0] = f2bf(a.x); r.u[1] = f2bf(a.y);
        r.u[2] = f2bf(a.z); r.u[3] = f2bf(a.w);
        r.u[4] = f2bf(b.x); r.u[5] = f2bf(b.y);
        r.u[6] = f2bf(b.z); r.u[7] = f2bf(b.w);
        *reinterpret_cast<short8*>(Kb + (size_t)i * 8) = r.v;
    }
}

// ---------------- main attention kernel (verbatim R9, verified) ----------------

#define MFMA_B16 __builtin_amdgcn_mfma_f32_32x32x16_bf16

__global__ __launch_bounds__(256, 2)
void attn_kernel(const float* __restrict__ Qf,            // [8192][256] fp32
                 const unsigned short* __restrict__ Kb,   // [8192][256] bf16
                 const unsigned short* __restrict__ VtG,  // [256][8192] bf16
                 __half* __restrict__ Opart,              // [NG][8192][256]
                 float* __restrict__ Ml,                  // [NG][8192][2]
                 int kv_span, int gshift) {
    // [buf][ K 16KB ] and [buf][ Vt 16KB ]  (tile = 32 kv)
    __shared__ __align__(16) unsigned char kbuf[2][16384];
    __shared__ __align__(16) unsigned char vbuf[2][16384];

    const int tid  = threadIdx.x;
    const int lane = tid & 63;
    const int w    = tid >> 6;     // 0..3
    const int l31  = lane & 31;
    const int h    = lane >> 5;    // 0/1

    const int ngm1 = (1 << gshift) - 1;
    const int id   = blockIdx.x + 64 * blockIdx.y;
    const int g    = id & ngm1;          // XCD-affine
    const int qblk = id >> gshift;       // 0..63
    const int kv_begin = g * kv_span;
    const int tiles = kv_span >> 5;
    const int q0 = qblk * 128 + w * 32;

    // Q as B-fragments, fp32 -> bf16 with scale log2(e)/16 (exp2 domain)
    const float qs = 0.09016844005556021f;
    short8 qf[16];
    {
        const float* qp = Qf + (size_t)(q0 + l31) * 256 + h * 8;
#pragma unroll
        for (int ds = 0; ds < 16; ++ds) {
            float4 f0 = *reinterpret_cast<const float4*>(qp + ds * 16);
            float4 f1 = *reinterpret_cast<const float4*>(qp + ds * 16 + 4);
            uint4 uu;
            uu.x = cvtpk_bf16(f0.x * qs, f0.y * qs);
            uu.y = cvtpk_bf16(f0.z * qs, f0.w * qs);
            uu.z = cvtpk_bf16(f1.x * qs, f1.y * qs);
            uu.w = cvtpk_bf16(f1.z * qs, f1.w * qs);
            qf[ds] = __builtin_bit_cast(short8, uu);
        }
    }

    floatx16 o[8];
#pragma unroll
    for (int vt = 0; vt < 8; ++vt)
#pragma unroll
        for (int r = 0; r < 16; ++r) o[vt][r] = 0.f;
    float m_run = -1e30f, l_run = 0.f;

    // staging offsets: 16B-chunk j = i*256 + tid
    //   K tile [32][512B]: rk = j>>5, src chunk = (j&31)^(rk&7)
    //   V tile [256][64B]: rv = j>>2, src chunk = (j&3)^((rv>>1)&3)
    int offk[4], offv[4];
#pragma unroll
    for (int i = 0; i < 4; ++i) {
        int j  = i * 256 + tid;
        int rk = j >> 5, ck = (j & 31) ^ (rk & 7);
        offk[i] = rk * 256 + ck * 8;
        int rv = j >> 2, cv = (j & 3) ^ ((rv >> 1) & 3);
        offv[i] = rv * 8192 + cv * 8;
    }

    auto STAGEK = [&](int kv0, int bufsel) {
        const unsigned short* ks = Kb + (size_t)kv0 * 256;
#pragma unroll
        for (int i = 0; i < 4; ++i)
            gload16(ks + offk[i], &kbuf[bufsel][(i * 256 + w * 64) * 16]);
    };
    auto STAGEV = [&](int kv0, int bufsel) {
        const unsigned short* vs = VtG + kv0;
#pragma unroll
        for (int i = 0; i < 4; ++i)
            gload16(vs + offv[i], &vbuf[bufsel][(i * 256 + w * 64) * 16]);
    };

    // ---- prologue: K(0) needed now, V(0) may stay in flight ----
    STAGEK(kv_begin, 0);     // 4 loads
    STAGEV(kv_begin, 0);     // 4 loads
    asm volatile("s_waitcnt vmcnt(4)" ::: "memory");   // K(0) landed
    __builtin_amdgcn_s_barrier();
    // invariant at iter entry: this wave's V(t) loads (4) outstanding

    const int swz  = l31 & 7;          // K-read swizzle
    const int vswz = (l31 >> 1) & 3;   // V-read swizzle

    auto buildPA = [&](const floatx16& sv, int rbase) -> short8 {
        unsigned cpk0 = cvtpk_bf16(sv[rbase + 0], sv[rbase + 1]);
        unsigned cpk1 = cvtpk_bf16(sv[rbase + 2], sv[rbase + 3]);
        unsigned cpk2 = cvtpk_bf16(sv[rbase + 4], sv[rbase + 5]);
        unsigned cpk3 = cvtpk_bf16(sv[rbase + 6], sv[rbase + 7]);
        uint4 uu;
#if __has_builtin(__builtin_amdgcn_permlane32_swap)
        auto r02 = __builtin_amdgcn_permlane32_swap((int)cpk0, (int)cpk2, false, false);
        auto r13 = __builtin_amdgcn_permlane32_swap((int)cpk1, (int)cpk3, false, false);
        uu.x = (unsigned)r02[0]; uu.y = (unsigned)r13[0];
        uu.z = (unsigned)r02[1]; uu.w = (unsigned)r13[1];
#else
        unsigned send0 = h ? cpk0 : cpk2;
        unsigned send1 = h ? cpk1 : cpk3;
        unsigned r0 = (unsigned)__shfl_xor((int)send0, 32);
        unsigned r1 = (unsigned)__shfl_xor((int)send1, 32);
        uu.x = h ? r0 : cpk0;
        uu.y = h ? r1 : cpk1;
        uu.z = h ? cpk2 : r0;
        uu.w = h ? cpk3 : r1;
#endif
        return __builtin_bit_cast(short8, uu);
    };

    for (int t = 0; t < tiles; ++t) {
        const int cur = t & 1;
        const int nxt = cur ^ 1;
        const int tn  = (t + 1 < tiles) ? t + 1 : t;  // clamp: dummy restage keeps counts uniform

        // ---- phase 1: issue K(t+1); QK^T + softmax on tile t ----
        STAGEK(kv_begin + tn * 32, nxt);
        // outstanding: V(t) 4 (oldest) + K(t+1) 4

        const unsigned char* kl = kbuf[cur];
        floatx16 sA, sB;
#pragma unroll
        for (int r = 0; r < 16; ++r) { sA[r] = 0.f; sB[r] = 0.f; }
        __builtin_amdgcn_s_setprio(1);
#pragma unroll
        for (int ds = 0; ds < 8; ++ds) {
            int c0 = (ds * 2 + h) ^ swz;
            short8 a0 = *reinterpret_cast<const short8*>(
                kl + (size_t)l31 * 512 + c0 * 16);
            sA = MFMA_B16(a0, qf[ds], sA, 0, 0, 0);
        }
#pragma unroll
        for (int ds = 8; ds < 16; ++ds) {
            int c0 = (ds * 2 + h) ^ swz;
            short8 a0 = *reinterpret_cast<const short8*>(
                kl + (size_t)l31 * 512 + c0 * 16);
            sB = MFMA_B16(a0, qf[ds], sB, 0, 0, 0);
        }
        __builtin_amdgcn_s_setprio(0);
        floatx16 s0;
#pragma unroll
        for (int r = 0; r < 16; ++r) s0[r] = sA[r] + sB[r];

        // ---- online softmax (exp2 domain, tree reductions) ----
        {
            float t4[4];
#pragma unroll
            for (int i = 0; i < 4; ++i)
                t4[i] = fmaxf(fmaxf(s0[i], s0[i + 4]),
                              fmaxf(s0[i + 8], s0[i + 12]));
            float mt = fmaxf(fmaxf(t4[0], t4[1]), fmaxf(t4[2], t4[3]));
            mt = fmaxf(mt, __shfl_xor(mt, 32));
            if (__any(mt > m_run + 11.5f)) {      // defer-max (log2 units)
                float mnew = fmaxf(m_run, mt);
                float al = EXP2F(m_run - mnew);
                m_run = mnew;
                l_run *= al;
#pragma unroll
                for (int reg = 0; reg < 16; ++reg) {
                    int srcl = ((reg & 3) + 8 * (reg >> 2)) + 4 * h;
                    float alr = __shfl(al, srcl);
#pragma unroll
                    for (int vt = 0; vt < 8; ++vt) o[vt][reg] *= alr;
                }
            }
#pragma unroll
            for (int r = 0; r < 16; ++r) s0[r] = EXP2F(s0[r] - m_run);
            float u[4];
#pragma unroll
            for (int i = 0; i < 4; ++i)
                u[i] = (s0[i] + s0[i + 4]) + (s0[i + 8] + s0[i + 12]);
            float lt = (u[0] + u[1]) + (u[2] + u[3]);
            lt += __shfl_xor(lt, 32);
            l_run += lt;
        }

        // V(t) must be visible to all waves before PV; K(t+1) stays in flight
        asm volatile("s_waitcnt vmcnt(4)" ::: "memory");
        __builtin_amdgcn_s_barrier();

        // ---- phase 2: issue V(t+1); PV on tile t ----
        STAGEV(kv_begin + tn * 32, nxt);
        // outstanding: K(t+1) 4 (oldest) + V(t+1) 4

        const unsigned char* vl = vbuf[cur];
        __builtin_amdgcn_s_setprio(1);
#pragma unroll
        for (int kk = 0; kk < 2; ++kk) {
            short8 pa = buildPA(s0, kk * 8);
            int cvs = (kk * 2 + h) ^ vswz;
#pragma unroll
            for (int vt = 0; vt < 8; ++vt) {
                short8 b = *reinterpret_cast<const short8*>(
                    vl + (size_t)(vt * 32 + l31) * 64 + cvs * 16);
                o[vt] = MFMA_B16(pa, b, o[vt], 0, 0, 0);
            }
        }
        __builtin_amdgcn_s_setprio(0);

        // K(t+1) must be visible before next iter's QK^T; V(t+1) stays in flight
        asm volatile("s_waitcnt vmcnt(4)" ::: "memory");
        __builtin_amdgcn_s_barrier();
    }

    // ---- epilogue: normalized fp16 partial + (m,l) fp32 ----
    const size_t gq = (size_t)g * 8192;
    float linv = 1.0f / l_run;
#pragma unroll
    for (int reg = 0; reg < 16; ++reg) {
        int row = (reg & 3) + 8 * (reg >> 2) + 4 * h;
        float li = __shfl(linv, row);
#pragma unroll
        for (int vt = 0; vt < 8; ++vt)
            Opart[(gq + q0 + row) * 256 + vt * 32 + l31] =
                __float2half_rn(o[vt][reg] * li);
    }
    if (h == 0) {
        size_t idx = (gq + q0 + l31) * 2;
        Ml[idx]     = m_run;   // log2 domain
        Ml[idx + 1] = l_run;
    }
}

// ---------------- merge kernel (half2-vectorized) ----------------

__global__ void merge_kernel(const __half* __restrict__ Opart,
                             const float* __restrict__ Ml,
                             float* __restrict__ out, int ngroups) {
    const int row = blockIdx.x;
    const int c2  = threadIdx.x;           // 0..127, col pair
    float m = -1e30f;
    for (int g = 0; g < ngroups; ++g)
        m = fmaxf(m, Ml[((size_t)g * 8192 + row) * 2]);
    float den = 0.f, ax = 0.f, ay = 0.f;
    for (int g = 0; g < ngroups; ++g) {
        float wg = EXP2F(Ml[((size_t)g * 8192 + row) * 2] - m) *
                   Ml[((size_t)g * 8192 + row) * 2 + 1];
        den += wg;
        __half2 h2 = *reinterpret_cast<const __half2*>(
            &Opart[((size_t)g * 8192 + row) * 256 + c2 * 2]);
        float2 f = __half22float2(h2);
        ax += wg * f.x;
        ay += wg * f.y;
    }
    float dinv = 1.0f / den;
    float2 r; r.x = ax * dinv; r.y = ay * dinv;
    *reinterpret_cast<float2*>(&out[(size_t)row * 256 + c2 * 2]) = r;
}

// ---------------- launcher ----------------

extern "C" void kernel_launch(void* const* d_in, const int* in_sizes, int n_in,
                              void* d_out, int out_size, void* d_ws, size_t ws_size,
                              hipStream_t stream) {
    const float* Q = (const float*)d_in[0];
    const float* K = (const float*)d_in[1];
    const float* V = (const float*)d_in[2];
    float* out = (float*)d_out;

    unsigned short* Kb = (unsigned short*)d_ws;            // 4 MiB
    unsigned short* Vt = Kb + (size_t)8192 * 256;          // 4 MiB

    const size_t base = (size_t)8192 * 256 * 2 * 2;        // 8 MiB
    const size_t osz  = (size_t)8192 * 256 * 2;            // 4 MiB/group (fp16)
    const size_t mlsz = (size_t)8192 * 2 * 4;              // 64 KiB/group

    int gshift = 3;
    for (; gshift > 0; --gshift)
        if (base + ((osz + mlsz) << gshift) <= ws_size) break;
    int ng = 1 << gshift;

    __half* Opart = (__half*)((char*)d_ws + base);
    float*  Mlp   = (float*)((char*)d_ws + base + osz * (size_t)ng);

    prep_kernel<<<dim3(128, 4), 256, 0, stream>>>(K, V, Kb, Vt);
    attn_kernel<<<dim3(64, ng), 256, 0, stream>>>(Q, Kb, Vt, Opart, Mlp,
                                                  8192 / ng, gshift);
    merge_kernel<<<8192, 128, 0, stream>>>(Opart, Mlp, out, ng);
}

// Round 15
// 122.624 us; speedup vs baseline: 4.8681x; 1.0102x over previous
//
#include <hip/hip_runtime.h>
#include <hip/hip_bf16.h>
#include <hip/hip_fp16.h>

// ScaledDotProductAttention N=M=8192, DK=DV=256, fp32 io.
// R15 = R14 + cross-tile MFMA pairing: P(t-1) held in registers (bf16
// pa-frags); body t runs QKT(t) interleaved 1:1 with PV(t-1) (independent
// MFMA clusters -> contiguous matrix-pipe stream), then SM(t) alone.
// Single-s QKT chain (16-deep) frees 16 regs for pa. One barrier/body.

typedef __attribute__((ext_vector_type(16))) float floatx16;
typedef __attribute__((ext_vector_type(8)))  short short8;

union S8u { short8 v; unsigned short u[8]; };

#if __has_builtin(__builtin_amdgcn_exp2f)
#define EXP2F(x) __builtin_amdgcn_exp2f(x)
#else
#define EXP2F(x) exp2f(x)
#endif

__device__ __forceinline__ unsigned short f2bf(float f) {
    unsigned int u = __builtin_bit_cast(unsigned int, f);
    unsigned int r = u + 0x7fffu + ((u >> 16) & 1u);   // RNE
    return (unsigned short)(r >> 16);
}

__device__ __forceinline__ unsigned cvtpk_bf16(float lo, float hi) {
    unsigned r;
    asm("v_cvt_pk_bf16_f32 %0, %1, %2" : "=v"(r) : "v"(lo), "v"(hi));
    return r;
}

__device__ __forceinline__ void gload16(const void* g, void* l) {
    __builtin_amdgcn_global_load_lds(
        (const __attribute__((address_space(1))) unsigned int*)g,
        (__attribute__((address_space(3))) unsigned int*)l, 16, 0, 0);
}

// ---------------- fused prep kernel: V transpose + K cvt ----------------

__global__ void prep_kernel(const float* __restrict__ K,
                            const float* __restrict__ V,
                            unsigned short* __restrict__ Kb,
                            unsigned short* __restrict__ Vt) {
    __shared__ unsigned short T[64][72];
    const int kv0 = blockIdx.x * 64;
    const int v0  = blockIdx.y * 64;
    const int tid = threadIdx.x;           // 256
#pragma unroll
    for (int it = 0; it < 4; ++it) {
        int flat = it * 256 + tid;
        int r  = flat >> 4;
        int c4 = (flat & 15) * 4;
        float4 f = *reinterpret_cast<const float4*>(
            V + (size_t)(kv0 + r) * 256 + v0 + c4);
        T[c4 + 0][r] = f2bf(f.x);
        T[c4 + 1][r] = f2bf(f.y);
        T[c4 + 2][r] = f2bf(f.z);
        T[c4 + 3][r] = f2bf(f.w);
    }
    __syncthreads();
#pragma unroll
    for (int it = 0; it < 2; ++it) {
        int flat = it * 256 + tid;
        int r  = flat >> 3;
        int c8 = (flat & 7) * 8;
        short8 v8 = *reinterpret_cast<const short8*>(&T[r][c8]);
        *reinterpret_cast<short8*>(Vt + (size_t)(v0 + r) * 8192 + kv0 + c8) = v8;
    }
    // ---- K conversion slice: 512 chunks-of-8 per block ----
    const int bid = blockIdx.x + 128 * blockIdx.y;   // 0..511
#pragma unroll
    for (int it = 0; it < 2; ++it) {
        int i = bid * 512 + it * 256 + tid;          // 0..262143
        const float4* p = reinterpret_cast<const float4*>(K) + (size_t)i * 2;
        float4 a = p[0], b = p[1];
        S8u r;
        r.u[0] = f2bf(a.x); r.u[1] = f2bf(a.y);
        r.u[2] = f2bf(a.z); r.u[3] = f2bf(a.w);
        r.u[4] = f2bf(b.x); r.u[5] = f2bf(b.y);
        r.u[6] = f2bf(b.z); r.u[7] = f2bf(b.w);
        *reinterpret_cast<short8*>(Kb + (size_t)i * 8) = r.v;
    }
}

// ---------------- main attention kernel ----------------

#define MFMA_B16 __builtin_amdgcn_mfma_f32_32x32x16_bf16

__global__ __launch_bounds__(256, 2)
void attn_kernel(const float* __restrict__ Qf,            // [8192][256] fp32
                 const unsigned short* __restrict__ Kb,   // [8192][256] bf16
                 const unsigned short* __restrict__ VtG,  // [256][8192] bf16
                 __half* __restrict__ Opart,              // [NG][8192][256]
                 float* __restrict__ Ml,                  // [NG][8192][2]
                 int kv_span, int gshift) {
    // [buf][ K 16KB ] and [buf][ Vt 16KB ]  (tile = 32 kv)
    __shared__ __align__(16) unsigned char kbuf[2][16384];
    __shared__ __align__(16) unsigned char vbuf[2][16384];

    const int tid  = threadIdx.x;
    const int lane = tid & 63;
    const int w    = tid >> 6;     // 0..3
    const int l31  = lane & 31;
    const int h    = lane >> 5;    // 0/1

    const int ngm1 = (1 << gshift) - 1;
    const int id   = blockIdx.x + 64 * blockIdx.y;
    const int g    = id & ngm1;          // XCD-affine
    const int qblk = id >> gshift;       // 0..63
    const int kv_begin = g * kv_span;
    const int tiles = kv_span >> 5;
    const int q0 = qblk * 128 + w * 32;

    // Q as B-fragments, fp32 -> bf16 with scale log2(e)/16 (exp2 domain)
    const float qs = 0.09016844005556021f;
    short8 qf[16];
    {
        const float* qp = Qf + (size_t)(q0 + l31) * 256 + h * 8;
#pragma unroll
        for (int ds = 0; ds < 16; ++ds) {
            float4 f0 = *reinterpret_cast<const float4*>(qp + ds * 16);
            float4 f1 = *reinterpret_cast<const float4*>(qp + ds * 16 + 4);
            uint4 uu;
            uu.x = cvtpk_bf16(f0.x * qs, f0.y * qs);
            uu.y = cvtpk_bf16(f0.z * qs, f0.w * qs);
            uu.z = cvtpk_bf16(f1.x * qs, f1.y * qs);
            uu.w = cvtpk_bf16(f1.z * qs, f1.w * qs);
            qf[ds] = __builtin_bit_cast(short8, uu);
        }
    }

    floatx16 o[8];
#pragma unroll
    for (int vt = 0; vt < 8; ++vt)
#pragma unroll
        for (int r = 0; r < 16; ++r) o[vt][r] = 0.f;
    float m_run = -1e30f, l_run = 0.f;

    // staging offsets (verified R9 maps): 16B-chunk j = i*256 + tid
    int offk[4], offv[4];
#pragma unroll
    for (int i = 0; i < 4; ++i) {
        int j  = i * 256 + tid;
        int rk = j >> 5, ck = (j & 31) ^ (rk & 7);
        offk[i] = rk * 256 + ck * 8;
        int rv = j >> 2, cv = (j & 3) ^ ((rv >> 1) & 3);
        offv[i] = rv * 8192 + cv * 8;
    }

    auto STAGEK = [&](int kv0, int bufsel) {
        const unsigned short* ks = Kb + (size_t)kv0 * 256;
#pragma unroll
        for (int i = 0; i < 4; ++i)
            gload16(ks + offk[i], &kbuf[bufsel][(i * 256 + w * 64) * 16]);
    };
    auto STAGEV = [&](int kv0, int bufsel) {
        const unsigned short* vs = VtG + kv0;
#pragma unroll
        for (int i = 0; i < 4; ++i)
            gload16(vs + offv[i], &vbuf[bufsel][(i * 256 + w * 64) * 16]);
    };

    // ---- prologue: K(0); V(0) into BOTH buffers (body-0 dummy PV reads
    // vbuf[1] with pa=0 -> real finite data, contributes exactly 0) ----
    STAGEK(kv_begin, 0);
    STAGEV(kv_begin, 0);
    STAGEV(kv_begin, 1);
    __syncthreads();

    const int swz  = l31 & 7;          // K-read swizzle
    const int vswz = (l31 >> 1) & 3;   // V-read swizzle

    auto buildPA = [&](const floatx16& sv, int rbase) -> short8 {
        unsigned cpk0 = cvtpk_bf16(sv[rbase + 0], sv[rbase + 1]);
        unsigned cpk1 = cvtpk_bf16(sv[rbase + 2], sv[rbase + 3]);
        unsigned cpk2 = cvtpk_bf16(sv[rbase + 4], sv[rbase + 5]);
        unsigned cpk3 = cvtpk_bf16(sv[rbase + 6], sv[rbase + 7]);
        uint4 uu;
#if __has_builtin(__builtin_amdgcn_permlane32_swap)
        auto r02 = __builtin_amdgcn_permlane32_swap((int)cpk0, (int)cpk2, false, false);
        auto r13 = __builtin_amdgcn_permlane32_swap((int)cpk1, (int)cpk3, false, false);
        uu.x = (unsigned)r02[0]; uu.y = (unsigned)r13[0];
        uu.z = (unsigned)r02[1]; uu.w = (unsigned)r13[1];
#else
        unsigned send0 = h ? cpk0 : cpk2;
        unsigned send1 = h ? cpk1 : cpk3;
        unsigned r0 = (unsigned)__shfl_xor((int)send0, 32);
        unsigned r1 = (unsigned)__shfl_xor((int)send1, 32);
        uu.x = h ? r0 : cpk0;
        uu.y = h ? r1 : cpk1;
        uu.z = h ? cpk2 : r0;
        uu.w = h ? cpk3 : r1;
#endif
        return __builtin_bit_cast(short8, uu);
    };

    // P(t-1) carried across bodies (zero for body 0 -> dummy PV adds 0)
    short8 pa0 = __builtin_bit_cast(short8, uint4{0u, 0u, 0u, 0u});
    short8 pa1 = pa0;

    for (int t = 0; t < tiles; ++t) {
        const int cur = t & 1;
        const int nxt = cur ^ 1;
        const int tn  = (t + 1 < tiles) ? t + 1 : t;   // dummy restage on last

        // ---- issue staging: K(t+1) and V(t); land by end of body ----
        STAGEK(kv_begin + tn * 32, nxt);
        STAGEV(kv_begin + t * 32, cur);

        const unsigned char* kl  = kbuf[cur];   // K(t)
        const unsigned char* vlp = vbuf[nxt];   // V(t-1)  ((t-1)&1 == nxt)

        // ---- QKT(t) interleaved 1:1 with PV(t-1): independent MFMAs ----
        floatx16 s;
#pragma unroll
        for (int r = 0; r < 16; ++r) s[r] = 0.f;
        __builtin_amdgcn_s_setprio(1);
#pragma unroll
        for (int ds = 0; ds < 16; ++ds) {
            int c0 = (ds * 2 + h) ^ swz;
            short8 a0 = *reinterpret_cast<const short8*>(
                kl + (size_t)l31 * 512 + c0 * 16);
            s = MFMA_B16(a0, qf[ds], s, 0, 0, 0);
            const int kk = ds >> 3, vt = ds & 7;
            int cvs = (kk * 2 + h) ^ vswz;
            short8 b = *reinterpret_cast<const short8*>(
                vlp + (size_t)(vt * 32 + l31) * 64 + cvs * 16);
            o[vt] = MFMA_B16(kk ? pa1 : pa0, b, o[vt], 0, 0, 0);
        }
        __builtin_amdgcn_s_setprio(0);

        // ---- online softmax on tile t (exp2 domain, tree reductions) ----
        {
            float t4[4];
#pragma unroll
            for (int i = 0; i < 4; ++i)
                t4[i] = fmaxf(fmaxf(s[i], s[i + 4]),
                              fmaxf(s[i + 8], s[i + 12]));
            float mt = fmaxf(fmaxf(t4[0], t4[1]), fmaxf(t4[2], t4[3]));
            mt = fmaxf(mt, __shfl_xor(mt, 32));
            if (__any(mt > m_run + 11.5f)) {      // defer-max (log2 units)
                float mnew = fmaxf(m_run, mt);
                float al = EXP2F(m_run - mnew);
                m_run = mnew;
                l_run *= al;
#pragma unroll
                for (int reg = 0; reg < 16; ++reg) {
                    int srcl = ((reg & 3) + 8 * (reg >> 2)) + 4 * h;
                    float alr = __shfl(al, srcl);
#pragma unroll
                    for (int vt = 0; vt < 8; ++vt) o[vt][reg] *= alr;
                }
            }
#pragma unroll
            for (int r = 0; r < 16; ++r) s[r] = EXP2F(s[r] - m_run);
            float u[4];
#pragma unroll
            for (int i = 0; i < 4; ++i)
                u[i] = (s[i] + s[i + 4]) + (s[i + 8] + s[i + 12]);
            float lt = (u[0] + u[1]) + (u[2] + u[3]);
            lt += __shfl_xor(lt, 32);
            l_run += lt;
        }
        pa0 = buildPA(s, 0);
        pa1 = buildPA(s, 8);

        // ---- drain this body's staging; rotate ----
        __syncthreads();
    }

    // ---- epilogue PV for the last tile ----
    {
        const unsigned char* vlq = vbuf[(tiles - 1) & 1];
        __builtin_amdgcn_s_setprio(1);
#pragma unroll
        for (int kk = 0; kk < 2; ++kk) {
            int cvs = (kk * 2 + h) ^ vswz;
#pragma unroll
            for (int vt = 0; vt < 8; ++vt) {
                short8 b = *reinterpret_cast<const short8*>(
                    vlq + (size_t)(vt * 32 + l31) * 64 + cvs * 16);
                o[vt] = MFMA_B16(kk ? pa1 : pa0, b, o[vt], 0, 0, 0);
            }
        }
        __builtin_amdgcn_s_setprio(0);
    }

    // ---- epilogue: normalized fp16 partial + (m,l) fp32 ----
    const size_t gq = (size_t)g * 8192;
    float linv = 1.0f / l_run;
#pragma unroll
    for (int reg = 0; reg < 16; ++reg) {
        int row = (reg & 3) + 8 * (reg >> 2) + 4 * h;
        float li = __shfl(linv, row);
#pragma unroll
        for (int vt = 0; vt < 8; ++vt)
            Opart[(gq + q0 + row) * 256 + vt * 32 + l31] =
                __float2half_rn(o[vt][reg] * li);
    }
    if (h == 0) {
        size_t idx = (gq + q0 + l31) * 2;
        Ml[idx]     = m_run;   // log2 domain
        Ml[idx + 1] = l_run;
    }
}

// ---------------- merge kernel (half2-vectorized) ----------------

__global__ void merge_kernel(const __half* __restrict__ Opart,
                             const float* __restrict__ Ml,
                             float* __restrict__ out, int ngroups) {
    const int row = blockIdx.x;
    const int c2  = threadIdx.x;           // 0..127, col pair
    float m = -1e30f;
    for (int g = 0; g < ngroups; ++g)
        m = fmaxf(m, Ml[((size_t)g * 8192 + row) * 2]);
    float den = 0.f, ax = 0.f, ay = 0.f;
    for (int g = 0; g < ngroups; ++g) {
        float wg = EXP2F(Ml[((size_t)g * 8192 + row) * 2] - m) *
                   Ml[((size_t)g * 8192 + row) * 2 + 1];
        den += wg;
        __half2 h2 = *reinterpret_cast<const __half2*>(
            &Opart[((size_t)g * 8192 + row) * 256 + c2 * 2]);
        float2 f = __half22float2(h2);
        ax += wg * f.x;
        ay += wg * f.y;
    }
    float dinv = 1.0f / den;
    float2 r; r.x = ax * dinv; r.y = ay * dinv;
    *reinterpret_cast<float2*>(&out[(size_t)row * 256 + c2 * 2]) = r;
}

// ---------------- launcher ----------------

extern "C" void kernel_launch(void* const* d_in, const int* in_sizes, int n_in,
                              void* d_out, int out_size, void* d_ws, size_t ws_size,
                              hipStream_t stream) {
    const float* Q = (const float*)d_in[0];
    const float* K = (const float*)d_in[1];
    const float* V = (const float*)d_in[2];
    float* out = (float*)d_out;

    unsigned short* Kb = (unsigned short*)d_ws;            // 4 MiB
    unsigned short* Vt = Kb + (size_t)8192 * 256;          // 4 MiB

    const size_t base = (size_t)8192 * 256 * 2 * 2;        // 8 MiB
    const size_t osz  = (size_t)8192 * 256 * 2;            // 4 MiB/group (fp16)
    const size_t mlsz = (size_t)8192 * 2 * 4;              // 64 KiB/group

    int gshift = 3;
    for (; gshift > 0; --gshift)
        if (base + ((osz + mlsz) << gshift) <= ws_size) break;
    int ng = 1 << gshift;

    __half* Opart = (__half*)((char*)d_ws + base);
    float*  Mlp   = (float*)((char*)d_ws + base + osz * (size_t)ng);

    prep_kernel<<<dim3(128, 4), 256, 0, stream>>>(K, V, Kb, Vt);
    attn_kernel<<<dim3(64, ng), 256, 0, stream>>>(Q, Kb, Vt, Opart, Mlp,
                                                  8192 / ng, gshift);
    merge_kernel<<<8192, 128, 0, stream>>>(Opart, Mlp, out, ng);
}